// Round 1
// baseline (905.387 us; speedup 1.0000x reference)
//
#include <hip/hip_runtime.h>

#define NH 12
#define DM 768
#define HD 64
#define BB 4
#define SS 1024
#define MTOT (BB*SS)          // 4096 rows
#define ATT_SCALE 0.125f      // 64^-0.5
#define NEGMASK (-4.0525551530189755e18f)   // -(3^39)

__device__ __forceinline__ float bf2f(unsigned short u){
    union { unsigned int i; float f; } x; x.i = ((unsigned int)u) << 16; return x.f;
}
__device__ __forceinline__ unsigned short f2bf(float f){
    union { float f; unsigned int i; } x; x.f = f;
    unsigned int i = x.i;
    return (unsigned short)((i + 0x7FFFu + ((i >> 16) & 1u)) >> 16);  // RNE
}

// ---------------------------------------------------------------------------
// Kernel 1: fused QKV projection.  out = (X @ W.T + b) [* scale for Q]
// X: [4096, 768] f32 row-major.  W: [768, 768] f32 row-major ([out,in]).
// Writes Q/K/V as bf16 in [B, H, S, HD] layout.
// Tiles: BM=BN=64, BK=16; 256 threads; 4x4 microtile per thread.
// ---------------------------------------------------------------------------
__global__ __launch_bounds__(256) void qkv_gemm(
    const float* __restrict__ X,
    const float* __restrict__ Wq, const float* __restrict__ bq,
    const float* __restrict__ Wk, const float* __restrict__ bk,
    const float* __restrict__ Wv, const float* __restrict__ bv,
    unsigned short* __restrict__ qout,
    unsigned short* __restrict__ kout,
    unsigned short* __restrict__ vout)
{
    const int nblk = blockIdx.x;          // 0..35 : which*12 + (n-block)
    const int m0   = blockIdx.y * 64;     // row block
    const int which = nblk / 12;
    const int n0    = (nblk % 12) * 64;

    const float* W    = (which == 0) ? Wq : (which == 1) ? Wk : Wv;
    const float* bias = (which == 0) ? bq : (which == 1) ? bk : bv;
    unsigned short* out = (which == 0) ? qout : (which == 1) ? kout : vout;
    const float scl = (which == 0) ? ATT_SCALE : 1.0f;

    __shared__ float As[64][17];   // [m][k], +1 pad
    __shared__ float Bs[64][17];   // [n][k], +1 pad

    const int t  = threadIdx.x;
    const int tx = t & 15;         // n-group
    const int ty = t >> 4;         // m-group
    const int lr = t >> 2;         // load row 0..63
    const int lc = (t & 3) * 4;    // load col {0,4,8,12}

    float c[4][4] = {};

    for (int kt = 0; kt < DM; kt += 16) {
        const float4 a4 = *(const float4*)&X[(size_t)(m0 + lr) * DM + kt + lc];
        const float4 b4 = *(const float4*)&W[(size_t)(n0 + lr) * DM + kt + lc];
        __syncthreads();
        As[lr][lc+0] = a4.x; As[lr][lc+1] = a4.y; As[lr][lc+2] = a4.z; As[lr][lc+3] = a4.w;
        Bs[lr][lc+0] = b4.x; Bs[lr][lc+1] = b4.y; Bs[lr][lc+2] = b4.z; Bs[lr][lc+3] = b4.w;
        __syncthreads();
        #pragma unroll
        for (int kk = 0; kk < 16; ++kk) {
            float av[4], bv4[4];
            #pragma unroll
            for (int i = 0; i < 4; ++i) av[i]  = As[ty*4 + i][kk];
            #pragma unroll
            for (int j = 0; j < 4; ++j) bv4[j] = Bs[tx*4 + j][kk];
            #pragma unroll
            for (int i = 0; i < 4; ++i)
                #pragma unroll
                for (int j = 0; j < 4; ++j)
                    c[i][j] = fmaf(av[i], bv4[j], c[i][j]);
        }
    }

    // epilogue: bias + optional scale, scatter to [B,H,S,HD] bf16
    #pragma unroll
    for (int i = 0; i < 4; ++i) {
        const int m = m0 + ty*4 + i;
        const int b = m >> 10;          // /1024
        const int s = m & 1023;
        #pragma unroll
        for (int j = 0; j < 4; ++j) {
            const int n  = n0 + tx*4 + j;
            const int h  = n >> 6;      // /64
            const int hd = n & 63;
            const float v = (c[i][j] + bias[n]) * scl;
            out[(((size_t)(b*NH + h))*SS + s)*HD + hd] = f2bf(v);
        }
    }
}

// ---------------------------------------------------------------------------
// Kernel 2: causal flash attention (fp32 compute, bf16 in/out).
// One block = (b,h) x 64-query tile. 256 threads. Key tiles of 32.
// ---------------------------------------------------------------------------
__global__ __launch_bounds__(256) void attn_kernel(
    const unsigned short* __restrict__ Q,   // [B,H,S,HD] bf16 (pre-scaled)
    const unsigned short* __restrict__ K,
    const unsigned short* __restrict__ V,
    unsigned short* __restrict__ O)         // [B,S,H*HD] bf16
{
    const int bh = blockIdx.x;              // 0..47
    const int qb = blockIdx.y * 64;         // query tile start
    const unsigned short* Qp = Q + (size_t)bh * SS * HD;
    const unsigned short* Kp = K + (size_t)bh * SS * HD;
    const unsigned short* Vp = V + (size_t)bh * SS * HD;

    __shared__ float Qs[64][65];
    __shared__ float Ks[32][65];
    __shared__ float Vs[32][64];
    __shared__ float Ss[64][33];
    __shared__ float sm_m[64], sm_l[64], sm_a[64];

    const int t  = threadIdx.x;
    const int dd = t & 63;      // owned head-dim column
    const int wv = t >> 6;      // wave index 0..3

    // stage Q tile (64x64)
    for (int idx = t; idx < 64*64; idx += 256)
        Qs[idx >> 6][idx & 63] = bf2f(Qp[(size_t)qb*HD + idx]);
    if (t < 64) { sm_m[t] = -INFINITY; sm_l[t] = 0.0f; }

    float acc[16] = {};          // this thread: q = wv*16+qq, d = dd

    const int ntile = (qb + 64) / 32;    // causal: keys up to qb+63
    for (int kt = 0; kt < ntile; ++kt) {
        const int k0 = kt * 32;
        __syncthreads();                 // protect Ks/Vs from prior readers
        for (int idx = t; idx < 32*64; idx += 256) {
            const int kk = idx >> 6, d = idx & 63;
            Ks[kk][d] = bf2f(Kp[(size_t)(k0 + kk)*HD + d]);
            Vs[kk][d] = bf2f(Vp[(size_t)(k0 + kk)*HD + d]);
        }
        __syncthreads();

        // scores: this thread does row q = t&63, cols wv*8 .. wv*8+7
        {
            const int q   = t & 63;
            const int kc0 = wv * 8;
            float s[8];
            #pragma unroll
            for (int j = 0; j < 8; ++j) s[j] = 0.0f;
            for (int d = 0; d < 64; ++d) {
                const float qv = Qs[q][d];
                #pragma unroll
                for (int j = 0; j < 8; ++j)
                    s[j] = fmaf(qv, Ks[kc0 + j][d], s[j]);
            }
            #pragma unroll
            for (int j = 0; j < 8; ++j) {
                const int gk = k0 + kc0 + j;
                float sv = s[j];
                if (gk > qb + q) sv += NEGMASK;     // reference mask semantics
                Ss[q][kc0 + j] = sv;
            }
        }
        __syncthreads();

        // online softmax per row (threads 0..63)
        if (t < 64) {
            const int q = t;
            const float mo = sm_m[q];
            float mx = mo;
            #pragma unroll
            for (int kk = 0; kk < 32; ++kk) mx = fmaxf(mx, Ss[q][kk]);
            const float alpha = __expf(mo - mx);    // mo=-inf first tile -> 0
            float sum = 0.0f;
            #pragma unroll
            for (int kk = 0; kk < 32; ++kk) {
                const float p = __expf(Ss[q][kk] - mx);
                Ss[q][kk] = p;
                sum += p;
            }
            sm_m[q] = mx;
            sm_l[q] = sm_l[q] * alpha + sum;
            sm_a[q] = alpha;
        }
        __syncthreads();

        // PV accumulate: acc[qq] = acc[qq]*alpha + sum_k P[q][k]*V[k][dd]
        #pragma unroll
        for (int qq = 0; qq < 16; ++qq) {
            const int q = wv*16 + qq;
            float a = acc[qq] * sm_a[q];
            #pragma unroll
            for (int kk = 0; kk < 32; ++kk)
                a = fmaf(Ss[q][kk], Vs[kk][dd], a);
            acc[qq] = a;
        }
    }
    __syncthreads();

    // epilogue: normalize, write [B,S,H*HD]
    const int b = bh / NH, h = bh % NH;
    #pragma unroll
    for (int qq = 0; qq < 16; ++qq) {
        const int q = wv*16 + qq;
        const float o = acc[qq] / sm_l[q];
        O[((size_t)(b*SS + qb + q))*DM + h*HD + dd] = f2bf(o);
    }
}

// ---------------------------------------------------------------------------
// Kernel 3: output projection. out = A @ Wo.T + bo (fp32 out)
// A: [4096,768] bf16.  Wo: [768,768] f32.
// ---------------------------------------------------------------------------
__global__ __launch_bounds__(256) void out_gemm(
    const unsigned short* __restrict__ A,
    const float* __restrict__ W, const float* __restrict__ bias,
    float* __restrict__ out)
{
    const int n0 = blockIdx.x * 64;
    const int m0 = blockIdx.y * 64;

    __shared__ float As[64][17];
    __shared__ float Bs[64][17];

    const int t  = threadIdx.x;
    const int tx = t & 15;
    const int ty = t >> 4;
    const int lr = t >> 2;
    const int lc = (t & 3) * 4;

    float c[4][4] = {};

    for (int kt = 0; kt < DM; kt += 16) {
        const unsigned short* ap = &A[(size_t)(m0 + lr) * DM + kt + lc];
        unsigned short a0 = ap[0], a1 = ap[1], a2 = ap[2], a3 = ap[3];
        const float4 b4 = *(const float4*)&W[(size_t)(n0 + lr) * DM + kt + lc];
        __syncthreads();
        As[lr][lc+0] = bf2f(a0); As[lr][lc+1] = bf2f(a1);
        As[lr][lc+2] = bf2f(a2); As[lr][lc+3] = bf2f(a3);
        Bs[lr][lc+0] = b4.x; Bs[lr][lc+1] = b4.y; Bs[lr][lc+2] = b4.z; Bs[lr][lc+3] = b4.w;
        __syncthreads();
        #pragma unroll
        for (int kk = 0; kk < 16; ++kk) {
            float av[4], bv4[4];
            #pragma unroll
            for (int i = 0; i < 4; ++i) av[i]  = As[ty*4 + i][kk];
            #pragma unroll
            for (int j = 0; j < 4; ++j) bv4[j] = Bs[tx*4 + j][kk];
            #pragma unroll
            for (int i = 0; i < 4; ++i)
                #pragma unroll
                for (int j = 0; j < 4; ++j)
                    c[i][j] = fmaf(av[i], bv4[j], c[i][j]);
        }
    }

    #pragma unroll
    for (int i = 0; i < 4; ++i) {
        const int m = m0 + ty*4 + i;
        float4 o;
        o.x = c[i][0] + bias[n0 + tx*4 + 0];
        o.y = c[i][1] + bias[n0 + tx*4 + 1];
        o.z = c[i][2] + bias[n0 + tx*4 + 2];
        o.w = c[i][3] + bias[n0 + tx*4 + 3];
        *(float4*)&out[(size_t)m * DM + n0 + tx*4] = o;
    }
}

// ---------------------------------------------------------------------------
extern "C" void kernel_launch(void* const* d_in, const int* in_sizes, int n_in,
                              void* d_out, int out_size, void* d_ws, size_t ws_size,
                              hipStream_t stream) {
    const float* X  = (const float*)d_in[0];
    const float* Wq = (const float*)d_in[1];
    const float* bq = (const float*)d_in[2];
    const float* Wk = (const float*)d_in[3];
    const float* bk = (const float*)d_in[4];
    const float* Wv = (const float*)d_in[5];
    const float* bv = (const float*)d_in[6];
    const float* Wo = (const float*)d_in[7];
    const float* bo = (const float*)d_in[8];
    float* out = (float*)d_out;

    const size_t elems = (size_t)MTOT * DM;       // 3,145,728
    unsigned short* q    = (unsigned short*)d_ws;
    unsigned short* k    = q    + elems;
    unsigned short* v    = k    + elems;
    unsigned short* attn = v    + elems;          // total 24 MB bf16

    qkv_gemm<<<dim3(36, 64), 256, 0, stream>>>(X, Wq, bq, Wk, bk, Wv, bv, q, k, v);
    attn_kernel<<<dim3(48, 16), 256, 0, stream>>>(q, k, v, attn);
    out_gemm<<<dim3(12, 64), 256, 0, stream>>>(attn, Wo, bo, out);
}

// Round 2
// 525.377 us; speedup vs baseline: 1.7233x; 1.7233x over previous
//
#include <hip/hip_runtime.h>

#define NH 12
#define DM 768
#define HD 64
#define BB 4
#define SS 1024
#define MTOT (BB*SS)          // 4096 rows
#define ATT_SCALE 0.125f      // 64^-0.5
#define NEGMASK (-4.0525551530189755e18f)   // -(3^39)

typedef __attribute__((ext_vector_type(8))) short short8;
typedef __attribute__((ext_vector_type(4))) float floatx4;

__device__ __forceinline__ float bf2f(unsigned short u){
    union { unsigned int i; float f; } x; x.i = ((unsigned int)u) << 16; return x.f;
}
__device__ __forceinline__ unsigned short f2bf(float f){
    union { float f; unsigned int i; } x; x.f = f;
    unsigned int i = x.i;
    return (unsigned short)((i + 0x7FFFu + ((i >> 16) & 1u)) >> 16);  // RNE
}

// ---------------------------------------------------------------------------
// Kernel 1: fused QKV projection.  out = (X @ W.T + b) [* scale for Q]
// (unchanged from round 1 — verified correct)
// ---------------------------------------------------------------------------
__global__ __launch_bounds__(256) void qkv_gemm(
    const float* __restrict__ X,
    const float* __restrict__ Wq, const float* __restrict__ bq,
    const float* __restrict__ Wk, const float* __restrict__ bk,
    const float* __restrict__ Wv, const float* __restrict__ bv,
    unsigned short* __restrict__ qout,
    unsigned short* __restrict__ kout,
    unsigned short* __restrict__ vout)
{
    const int nblk = blockIdx.x;          // 0..35 : which*12 + (n-block)
    const int m0   = blockIdx.y * 64;     // row block
    const int which = nblk / 12;
    const int n0    = (nblk % 12) * 64;

    const float* W    = (which == 0) ? Wq : (which == 1) ? Wk : Wv;
    const float* bias = (which == 0) ? bq : (which == 1) ? bk : bv;
    unsigned short* out = (which == 0) ? qout : (which == 1) ? kout : vout;
    const float scl = (which == 0) ? ATT_SCALE : 1.0f;

    __shared__ float As[64][17];   // [m][k], +1 pad
    __shared__ float Bs[64][17];   // [n][k], +1 pad

    const int t  = threadIdx.x;
    const int tx = t & 15;         // n-group
    const int ty = t >> 4;         // m-group
    const int lr = t >> 2;         // load row 0..63
    const int lc = (t & 3) * 4;    // load col {0,4,8,12}

    float c[4][4] = {};

    for (int kt = 0; kt < DM; kt += 16) {
        const float4 a4 = *(const float4*)&X[(size_t)(m0 + lr) * DM + kt + lc];
        const float4 b4 = *(const float4*)&W[(size_t)(n0 + lr) * DM + kt + lc];
        __syncthreads();
        As[lr][lc+0] = a4.x; As[lr][lc+1] = a4.y; As[lr][lc+2] = a4.z; As[lr][lc+3] = a4.w;
        Bs[lr][lc+0] = b4.x; Bs[lr][lc+1] = b4.y; Bs[lr][lc+2] = b4.z; Bs[lr][lc+3] = b4.w;
        __syncthreads();
        #pragma unroll
        for (int kk = 0; kk < 16; ++kk) {
            float av[4], bv4[4];
            #pragma unroll
            for (int i = 0; i < 4; ++i) av[i]  = As[ty*4 + i][kk];
            #pragma unroll
            for (int j = 0; j < 4; ++j) bv4[j] = Bs[tx*4 + j][kk];
            #pragma unroll
            for (int i = 0; i < 4; ++i)
                #pragma unroll
                for (int j = 0; j < 4; ++j)
                    c[i][j] = fmaf(av[i], bv4[j], c[i][j]);
        }
    }

    #pragma unroll
    for (int i = 0; i < 4; ++i) {
        const int m = m0 + ty*4 + i;
        const int b = m >> 10;          // /1024
        const int s = m & 1023;
        #pragma unroll
        for (int j = 0; j < 4; ++j) {
            const int n  = n0 + tx*4 + j;
            const int h  = n >> 6;      // /64
            const int hd = n & 63;
            const float v = (c[i][j] + bias[n]) * scl;
            out[(((size_t)(b*NH + h))*SS + s)*HD + hd] = f2bf(v);
        }
    }
}

// ---------------------------------------------------------------------------
// Kernel 2: causal flash attention on MFMA (bf16 in, fp32 acc, bf16 out).
// One block = (b,h) x 64-query tile; 4 waves, each owning 16 q rows.
// K-tiles of 64. Q/K fragments loaded straight from global (contiguous in
// [S,HD] layout); V transposed into LDS; P round-trips through per-wave LDS
// to convert C/D layout -> A-operand layout.
// ---------------------------------------------------------------------------
__global__ __launch_bounds__(256) void attn_mfma(
    const unsigned short* __restrict__ Q,   // [B,H,S,HD] bf16 (pre-scaled)
    const unsigned short* __restrict__ K,
    const unsigned short* __restrict__ V,
    unsigned short* __restrict__ O)         // [B,S,H*HD] bf16
{
    const int bh = blockIdx.x;              // 0..47
    const int qb = blockIdx.y * 64;         // query tile start
    const unsigned short* Qp = Q + (size_t)bh * SS * HD;
    const unsigned short* Kp = K + (size_t)bh * SS * HD;
    const unsigned short* Vp = V + (size_t)bh * SS * HD;

    __shared__ unsigned short Vt[64 * 72];        // [d][k], stride 72 bf16
    __shared__ unsigned short Pl[4][16 * 72];     // per-wave P [q][k], stride 72

    const int t    = threadIdx.x;
    const int w    = t >> 6;       // wave 0..3 -> q rows [qb+16w, qb+16w+16)
    const int lane = t & 63;
    const int c    = lane & 15;    // A/B-frag m/n index; C-frag col
    const int g    = lane >> 4;    // quad 0..3

    // Q A-fragments (held in registers for the whole kernel):
    // lane holds Q[qb + 16w + c][g*8 + j + 32*st]
    short8 qf[2];
    #pragma unroll
    for (int st = 0; st < 2; ++st)
        qf[st] = *(const short8*)(Qp + (size_t)(qb + w*16 + c) * HD + g*8 + 32*st);

    floatx4 Oacc[4] = {};          // C layout: row=g*4+r (q), col=nf*16+c (d)
    float m_r[4], l_r[4];
    #pragma unroll
    for (int r = 0; r < 4; ++r) { m_r[r] = -INFINITY; l_r[r] = 0.0f; }

    const int ntile = qb / 64 + 1;              // causal: keys up to qb+63
    for (int kt = 0; kt < ntile; ++kt) {
        const int k0 = kt * 64;

        __syncthreads();                         // protect Vt from prior readers
        {   // stage V^T: thread t loads 16 bf16 of V row (t>>2), cols (t&3)*16..
            const int kk = t >> 2;
            const int d0 = (t & 3) * 16;
            const unsigned short* vp = Vp + (size_t)(k0 + kk) * HD + d0;
            short8 v0 = *(const short8*)(vp);
            short8 v1 = *(const short8*)(vp + 8);
            #pragma unroll
            for (int j = 0; j < 8; ++j) {
                Vt[(d0 + j    ) * 72 + kk] = (unsigned short)v0[j];
                Vt[(d0 + j + 8) * 72 + kk] = (unsigned short)v1[j];
            }
        }
        __syncthreads();

        // ---- S = Q K^T for this wave's 16 rows x 64 cols ----
        floatx4 Sacc[4] = {};
        #pragma unroll
        for (int nf = 0; nf < 4; ++nf) {
            #pragma unroll
            for (int st = 0; st < 2; ++st) {
                const short8 kf = *(const short8*)(Kp + (size_t)(k0 + nf*16 + c) * HD + g*8 + 32*st);
                Sacc[nf] = __builtin_amdgcn_mfma_f32_16x16x32_bf16(qf[st], kf, Sacc[nf], 0, 0, 0);
            }
        }

        // ---- causal mask (only on tiles overlapping the diagonal) ----
        if (k0 + 63 > qb + w*16) {
            #pragma unroll
            for (int nf = 0; nf < 4; ++nf) {
                const int col = k0 + nf*16 + c;
                #pragma unroll
                for (int r = 0; r < 4; ++r) {
                    const int row = qb + w*16 + g*4 + r;
                    if (col > row) Sacc[nf][r] += NEGMASK;
                }
            }
        }

        // ---- online softmax, per row r (rows live across 16-lane groups) ----
        float alpha[4];
        #pragma unroll
        for (int r = 0; r < 4; ++r) {
            float mx = Sacc[0][r];
            mx = fmaxf(mx, Sacc[1][r]);
            mx = fmaxf(mx, Sacc[2][r]);
            mx = fmaxf(mx, Sacc[3][r]);
            #pragma unroll
            for (int msk = 1; msk < 16; msk <<= 1)
                mx = fmaxf(mx, __shfl_xor(mx, msk, 64));
            const float mnew = fmaxf(m_r[r], mx);
            alpha[r] = __expf(m_r[r] - mnew);
            float sum = 0.0f;
            #pragma unroll
            for (int nf = 0; nf < 4; ++nf) {
                const float p = __expf(Sacc[nf][r] - mnew);
                Sacc[nf][r] = p;
                sum += p;
            }
            #pragma unroll
            for (int msk = 1; msk < 16; msk <<= 1)
                sum += __shfl_xor(sum, msk, 64);
            l_r[r] = l_r[r] * alpha[r] + sum;
            m_r[r] = mnew;
            #pragma unroll
            for (int nf = 0; nf < 4; ++nf) Oacc[nf][r] *= alpha[r];
        }

        // ---- P: C layout -> LDS (bf16) -> A-operand layout ----
        unsigned short* pw = Pl[w];
        #pragma unroll
        for (int r = 0; r < 4; ++r)
            #pragma unroll
            for (int nf = 0; nf < 4; ++nf)
                pw[(g*4 + r) * 72 + nf*16 + c] = f2bf(Sacc[nf][r]);
        // per-wave region + in-order DS pipe: no cross-wave barrier needed

        // ---- O += P V ----
        #pragma unroll
        for (int st = 0; st < 2; ++st) {
            const short8 pf = *(const short8*)(pw + c * 72 + g*8 + 32*st);
            #pragma unroll
            for (int nf = 0; nf < 4; ++nf) {
                const short8 vf = *(const short8*)(Vt + (nf*16 + c) * 72 + g*8 + 32*st);
                Oacc[nf] = __builtin_amdgcn_mfma_f32_16x16x32_bf16(pf, vf, Oacc[nf], 0, 0, 0);
            }
        }
    }

    // ---- epilogue: normalize, write [B,S,H*HD] bf16 ----
    const int b = bh / NH, h = bh % NH;
    #pragma unroll
    for (int r = 0; r < 4; ++r) {
        const float inv = 1.0f / l_r[r];
        const int s = qb + w*16 + g*4 + r;
        #pragma unroll
        for (int nf = 0; nf < 4; ++nf)
            O[((size_t)(b*SS + s))*DM + h*HD + nf*16 + c] = f2bf(Oacc[nf][r] * inv);
    }
}

// ---------------------------------------------------------------------------
// Kernel 3: output projection. out = A @ Wo.T + bo (fp32 out)
// (unchanged from round 1 — verified correct)
// ---------------------------------------------------------------------------
__global__ __launch_bounds__(256) void out_gemm(
    const unsigned short* __restrict__ A,
    const float* __restrict__ W, const float* __restrict__ bias,
    float* __restrict__ out)
{
    const int n0 = blockIdx.x * 64;
    const int m0 = blockIdx.y * 64;

    __shared__ float As[64][17];
    __shared__ float Bs[64][17];

    const int t  = threadIdx.x;
    const int tx = t & 15;
    const int ty = t >> 4;
    const int lr = t >> 2;
    const int lc = (t & 3) * 4;

    float c[4][4] = {};

    for (int kt = 0; kt < DM; kt += 16) {
        const unsigned short* ap = &A[(size_t)(m0 + lr) * DM + kt + lc];
        unsigned short a0 = ap[0], a1 = ap[1], a2 = ap[2], a3 = ap[3];
        const float4 b4 = *(const float4*)&W[(size_t)(n0 + lr) * DM + kt + lc];
        __syncthreads();
        As[lr][lc+0] = bf2f(a0); As[lr][lc+1] = bf2f(a1);
        As[lr][lc+2] = bf2f(a2); As[lr][lc+3] = bf2f(a3);
        Bs[lr][lc+0] = b4.x; Bs[lr][lc+1] = b4.y; Bs[lr][lc+2] = b4.z; Bs[lr][lc+3] = b4.w;
        __syncthreads();
        #pragma unroll
        for (int kk = 0; kk < 16; ++kk) {
            float av[4], bv4[4];
            #pragma unroll
            for (int i = 0; i < 4; ++i) av[i]  = As[ty*4 + i][kk];
            #pragma unroll
            for (int j = 0; j < 4; ++j) bv4[j] = Bs[tx*4 + j][kk];
            #pragma unroll
            for (int i = 0; i < 4; ++i)
                #pragma unroll
                for (int j = 0; j < 4; ++j)
                    c[i][j] = fmaf(av[i], bv4[j], c[i][j]);
        }
    }

    #pragma unroll
    for (int i = 0; i < 4; ++i) {
        const int m = m0 + ty*4 + i;
        float4 o;
        o.x = c[i][0] + bias[n0 + tx*4 + 0];
        o.y = c[i][1] + bias[n0 + tx*4 + 1];
        o.z = c[i][2] + bias[n0 + tx*4 + 2];
        o.w = c[i][3] + bias[n0 + tx*4 + 3];
        *(float4*)&out[(size_t)m * DM + n0 + tx*4] = o;
    }
}

// ---------------------------------------------------------------------------
extern "C" void kernel_launch(void* const* d_in, const int* in_sizes, int n_in,
                              void* d_out, int out_size, void* d_ws, size_t ws_size,
                              hipStream_t stream) {
    const float* X  = (const float*)d_in[0];
    const float* Wq = (const float*)d_in[1];
    const float* bq = (const float*)d_in[2];
    const float* Wk = (const float*)d_in[3];
    const float* bk = (const float*)d_in[4];
    const float* Wv = (const float*)d_in[5];
    const float* bv = (const float*)d_in[6];
    const float* Wo = (const float*)d_in[7];
    const float* bo = (const float*)d_in[8];
    float* out = (float*)d_out;

    const size_t elems = (size_t)MTOT * DM;       // 3,145,728
    unsigned short* q    = (unsigned short*)d_ws;
    unsigned short* k    = q    + elems;
    unsigned short* v    = k    + elems;
    unsigned short* attn = v    + elems;          // total 24 MB bf16

    qkv_gemm<<<dim3(36, 64), 256, 0, stream>>>(X, Wq, bq, Wk, bk, Wv, bv, q, k, v);
    attn_mfma<<<dim3(48, 16), 256, 0, stream>>>(q, k, v, attn);
    out_gemm<<<dim3(12, 64), 256, 0, stream>>>(attn, Wo, bo, out);
}

// Round 3
// 181.261 us; speedup vs baseline: 4.9949x; 2.8985x over previous
//
#include <hip/hip_runtime.h>

#define NH 12
#define DM 768
#define HD 64
#define BB 4
#define SS 1024
#define MTOT (BB*SS)          // 4096 rows
#define ATT_SCALE 0.125f      // 64^-0.5
#define NEGMASK (-4.0525551530189755e18f)   // -(3^39)

typedef __attribute__((ext_vector_type(8))) short short8;
typedef __attribute__((ext_vector_type(4))) float floatx4;
typedef __attribute__((ext_vector_type(4))) unsigned short ushort4v;

__device__ __forceinline__ float bf2f(unsigned short u){
    union { unsigned int i; float f; } x; x.i = ((unsigned int)u) << 16; return x.f;
}
__device__ __forceinline__ unsigned short f2bf(float f){
    union { float f; unsigned int i; } x; x.f = f;
    unsigned int i = x.i;
    return (unsigned short)((i + 0x7FFFu + ((i >> 16) & 1u)) >> 16);  // RNE
}

// ---------------------------------------------------------------------------
// Kernel 0: fp32 -> bf16 conversion of X and the 4 weight matrices.
// ---------------------------------------------------------------------------
#define XQ4 (MTOT*DM/4)   // 786432 float4 groups in X
#define WQ4 (DM*DM/4)     // 147456 float4 groups per weight

__global__ __launch_bounds__(256) void convert_bf16(
    const float* __restrict__ X,
    const float* __restrict__ Wq, const float* __restrict__ Wk,
    const float* __restrict__ Wv, const float* __restrict__ Wo,
    unsigned short* __restrict__ Xb,
    unsigned short* __restrict__ Wqb, unsigned short* __restrict__ Wkb,
    unsigned short* __restrict__ Wvb, unsigned short* __restrict__ Wob)
{
    const int idx = blockIdx.x * 256 + threadIdx.x;
    const float* s; unsigned short* d; int off;
    if (idx < XQ4) { s = X; d = Xb; off = idx; }
    else {
        const int r = idx - XQ4;
        const int wsel = r / WQ4;
        off = r - wsel * WQ4;
        s = (wsel==0)?Wq:(wsel==1)?Wk:(wsel==2)?Wv:Wo;
        d = (wsel==0)?Wqb:(wsel==1)?Wkb:(wsel==2)?Wvb:Wob;
    }
    const float4 v = ((const float4*)s)[off];
    ushort4v o;
    o[0] = f2bf(v.x); o[1] = f2bf(v.y); o[2] = f2bf(v.z); o[3] = f2bf(v.w);
    ((ushort4v*)d)[off] = o;
}

// ---------------------------------------------------------------------------
// Kernel 1: fused QKV projection on MFMA.  out = (Xb @ Wb.T + b) [* scale]
// 128x128 tile, BK=32, 4 waves (2x2 of 64x64), global_load_lds staging.
// LDS layout [row][32 k-elems] unpadded (global_load_lds constraint).
// ---------------------------------------------------------------------------
__global__ __launch_bounds__(256) void qkv_mfma(
    const unsigned short* __restrict__ Xb,   // [4096,768] bf16
    const unsigned short* __restrict__ Wqb,
    const unsigned short* __restrict__ Wkb,
    const unsigned short* __restrict__ Wvb,
    const float* __restrict__ bq, const float* __restrict__ bk,
    const float* __restrict__ bv,
    unsigned short* __restrict__ qout,
    unsigned short* __restrict__ kout,
    unsigned short* __restrict__ vout)
{
    const int which = blockIdx.z;
    const int n0 = blockIdx.x * 128;
    const int m0 = blockIdx.y * 128;
    const unsigned short* W = (which==0) ? Wqb : (which==1) ? Wkb : Wvb;
    const float* bias = (which==0) ? bq : (which==1) ? bk : bv;
    unsigned short* out = (which==0) ? qout : (which==1) ? kout : vout;
    const float scl = (which==0) ? ATT_SCALE : 1.0f;

    __shared__ unsigned short As[128*32];   // 8 KB
    __shared__ unsigned short Bs[128*32];   // 8 KB

    const int t = threadIdx.x;
    const int w = t >> 6, lane = t & 63;
    const int c = lane & 15, g = lane >> 4;
    const int wr = w >> 1, wc = w & 1;

    floatx4 acc[4][4] = {};

    const int srow = lane >> 2;          // 0..15: row within 16-row staging slab
    const int ske  = (lane & 3) * 8;     // k-element offset: lds off = lane*8

    for (int k0 = 0; k0 < DM; k0 += 32) {
        __syncthreads();
        #pragma unroll
        for (int j = 0; j < 2; ++j) {
            const int row = w*32 + j*16 + srow;
            __builtin_amdgcn_global_load_lds(
                (const __attribute__((address_space(1))) unsigned int*)
                    (Xb + (size_t)(m0 + row) * DM + k0 + ske),
                (__attribute__((address_space(3))) unsigned int*)
                    (As + (w*32 + j*16) * 32),
                16, 0, 0);
            __builtin_amdgcn_global_load_lds(
                (const __attribute__((address_space(1))) unsigned int*)
                    (W + (size_t)(n0 + row) * DM + k0 + ske),
                (__attribute__((address_space(3))) unsigned int*)
                    (Bs + (w*32 + j*16) * 32),
                16, 0, 0);
        }
        __syncthreads();

        short8 af[4], bfr[4];
        #pragma unroll
        for (int mi = 0; mi < 4; ++mi)
            af[mi] = *(const short8*)(As + (wr*64 + mi*16 + c)*32 + g*8);
        #pragma unroll
        for (int ni = 0; ni < 4; ++ni)
            bfr[ni] = *(const short8*)(Bs + (wc*64 + ni*16 + c)*32 + g*8);
        #pragma unroll
        for (int mi = 0; mi < 4; ++mi)
            #pragma unroll
            for (int ni = 0; ni < 4; ++ni)
                acc[mi][ni] = __builtin_amdgcn_mfma_f32_16x16x32_bf16(
                    af[mi], bfr[ni], acc[mi][ni], 0, 0, 0);
    }

    // epilogue: bias + scale, scatter to [B,H,S,HD] bf16
    #pragma unroll
    for (int mi = 0; mi < 4; ++mi) {
        #pragma unroll
        for (int r = 0; r < 4; ++r) {
            const int m = m0 + wr*64 + mi*16 + g*4 + r;
            const int b = m >> 10, s = m & 1023;
            #pragma unroll
            for (int ni = 0; ni < 4; ++ni) {
                const int n = n0 + wc*64 + ni*16 + c;
                const int h = n >> 6, hd = n & 63;
                const float val = (acc[mi][ni][r] + bias[n]) * scl;
                out[(((size_t)(b*NH + h))*SS + s)*HD + hd] = f2bf(val);
            }
        }
    }
}

// ---------------------------------------------------------------------------
// Kernel 2: causal flash attention on MFMA (unchanged from round 2 — verified)
// ---------------------------------------------------------------------------
__global__ __launch_bounds__(256) void attn_mfma(
    const unsigned short* __restrict__ Q,   // [B,H,S,HD] bf16 (pre-scaled)
    const unsigned short* __restrict__ K,
    const unsigned short* __restrict__ V,
    unsigned short* __restrict__ O)         // [B,S,H*HD] bf16
{
    const int bh = blockIdx.x;              // 0..47
    const int qb = blockIdx.y * 64;         // query tile start
    const unsigned short* Qp = Q + (size_t)bh * SS * HD;
    const unsigned short* Kp = K + (size_t)bh * SS * HD;
    const unsigned short* Vp = V + (size_t)bh * SS * HD;

    __shared__ unsigned short Vt[64 * 72];        // [d][k], stride 72 bf16
    __shared__ unsigned short Pl[4][16 * 72];     // per-wave P [q][k], stride 72

    const int t    = threadIdx.x;
    const int w    = t >> 6;       // wave 0..3 -> q rows [qb+16w, qb+16w+16)
    const int lane = t & 63;
    const int c    = lane & 15;    // A/B-frag m/n index; C-frag col
    const int g    = lane >> 4;    // quad 0..3

    short8 qf[2];
    #pragma unroll
    for (int st = 0; st < 2; ++st)
        qf[st] = *(const short8*)(Qp + (size_t)(qb + w*16 + c) * HD + g*8 + 32*st);

    floatx4 Oacc[4] = {};          // C layout: row=g*4+r (q), col=nf*16+c (d)
    float m_r[4], l_r[4];
    #pragma unroll
    for (int r = 0; r < 4; ++r) { m_r[r] = -INFINITY; l_r[r] = 0.0f; }

    const int ntile = qb / 64 + 1;              // causal: keys up to qb+63
    for (int kt = 0; kt < ntile; ++kt) {
        const int k0 = kt * 64;

        __syncthreads();                         // protect Vt from prior readers
        {   // stage V^T
            const int kk = t >> 2;
            const int d0 = (t & 3) * 16;
            const unsigned short* vp = Vp + (size_t)(k0 + kk) * HD + d0;
            short8 v0 = *(const short8*)(vp);
            short8 v1 = *(const short8*)(vp + 8);
            #pragma unroll
            for (int j = 0; j < 8; ++j) {
                Vt[(d0 + j    ) * 72 + kk] = (unsigned short)v0[j];
                Vt[(d0 + j + 8) * 72 + kk] = (unsigned short)v1[j];
            }
        }
        __syncthreads();

        // ---- S = Q K^T for this wave's 16 rows x 64 cols ----
        floatx4 Sacc[4] = {};
        #pragma unroll
        for (int nf = 0; nf < 4; ++nf) {
            #pragma unroll
            for (int st = 0; st < 2; ++st) {
                const short8 kf = *(const short8*)(Kp + (size_t)(k0 + nf*16 + c) * HD + g*8 + 32*st);
                Sacc[nf] = __builtin_amdgcn_mfma_f32_16x16x32_bf16(qf[st], kf, Sacc[nf], 0, 0, 0);
            }
        }

        // ---- causal mask ----
        if (k0 + 63 > qb + w*16) {
            #pragma unroll
            for (int nf = 0; nf < 4; ++nf) {
                const int col = k0 + nf*16 + c;
                #pragma unroll
                for (int r = 0; r < 4; ++r) {
                    const int row = qb + w*16 + g*4 + r;
                    if (col > row) Sacc[nf][r] += NEGMASK;
                }
            }
        }

        // ---- online softmax, per row r ----
        float alpha[4];
        #pragma unroll
        for (int r = 0; r < 4; ++r) {
            float mx = Sacc[0][r];
            mx = fmaxf(mx, Sacc[1][r]);
            mx = fmaxf(mx, Sacc[2][r]);
            mx = fmaxf(mx, Sacc[3][r]);
            #pragma unroll
            for (int msk = 1; msk < 16; msk <<= 1)
                mx = fmaxf(mx, __shfl_xor(mx, msk, 64));
            const float mnew = fmaxf(m_r[r], mx);
            alpha[r] = __expf(m_r[r] - mnew);
            float sum = 0.0f;
            #pragma unroll
            for (int nf = 0; nf < 4; ++nf) {
                const float p = __expf(Sacc[nf][r] - mnew);
                Sacc[nf][r] = p;
                sum += p;
            }
            #pragma unroll
            for (int msk = 1; msk < 16; msk <<= 1)
                sum += __shfl_xor(sum, msk, 64);
            l_r[r] = l_r[r] * alpha[r] + sum;
            m_r[r] = mnew;
            #pragma unroll
            for (int nf = 0; nf < 4; ++nf) Oacc[nf][r] *= alpha[r];
        }

        // ---- P: C layout -> LDS (bf16) -> A-operand layout ----
        unsigned short* pw = Pl[w];
        #pragma unroll
        for (int r = 0; r < 4; ++r)
            #pragma unroll
            for (int nf = 0; nf < 4; ++nf)
                pw[(g*4 + r) * 72 + nf*16 + c] = f2bf(Sacc[nf][r]);

        // ---- O += P V ----
        #pragma unroll
        for (int st = 0; st < 2; ++st) {
            const short8 pf = *(const short8*)(pw + c * 72 + g*8 + 32*st);
            #pragma unroll
            for (int nf = 0; nf < 4; ++nf) {
                const short8 vf = *(const short8*)(Vt + (nf*16 + c) * 72 + g*8 + 32*st);
                Oacc[nf] = __builtin_amdgcn_mfma_f32_16x16x32_bf16(pf, vf, Oacc[nf], 0, 0, 0);
            }
        }
    }

    // ---- epilogue ----
    const int b = bh / NH, h = bh % NH;
    #pragma unroll
    for (int r = 0; r < 4; ++r) {
        const float inv = 1.0f / l_r[r];
        const int s = qb + w*16 + g*4 + r;
        #pragma unroll
        for (int nf = 0; nf < 4; ++nf)
            O[((size_t)(b*SS + s))*DM + h*HD + nf*16 + c] = f2bf(Oacc[nf][r] * inv);
    }
}

// ---------------------------------------------------------------------------
// Kernel 3: output projection on MFMA. out = A @ Wo.T + bo (fp32 out)
// Same structure as qkv_mfma; fp32 epilogue.
// ---------------------------------------------------------------------------
__global__ __launch_bounds__(256) void out_mfma(
    const unsigned short* __restrict__ A,    // [4096,768] bf16
    const unsigned short* __restrict__ Wb,   // [768,768] bf16
    const float* __restrict__ bias,
    float* __restrict__ outf)
{
    const int n0 = blockIdx.x * 128;
    const int m0 = blockIdx.y * 128;

    __shared__ unsigned short As[128*32];
    __shared__ unsigned short Bs[128*32];

    const int t = threadIdx.x;
    const int w = t >> 6, lane = t & 63;
    const int c = lane & 15, g = lane >> 4;
    const int wr = w >> 1, wc = w & 1;

    floatx4 acc[4][4] = {};

    const int srow = lane >> 2;
    const int ske  = (lane & 3) * 8;

    for (int k0 = 0; k0 < DM; k0 += 32) {
        __syncthreads();
        #pragma unroll
        for (int j = 0; j < 2; ++j) {
            const int row = w*32 + j*16 + srow;
            __builtin_amdgcn_global_load_lds(
                (const __attribute__((address_space(1))) unsigned int*)
                    (A + (size_t)(m0 + row) * DM + k0 + ske),
                (__attribute__((address_space(3))) unsigned int*)
                    (As + (w*32 + j*16) * 32),
                16, 0, 0);
            __builtin_amdgcn_global_load_lds(
                (const __attribute__((address_space(1))) unsigned int*)
                    (Wb + (size_t)(n0 + row) * DM + k0 + ske),
                (__attribute__((address_space(3))) unsigned int*)
                    (Bs + (w*32 + j*16) * 32),
                16, 0, 0);
        }
        __syncthreads();

        short8 af[4], bfr[4];
        #pragma unroll
        for (int mi = 0; mi < 4; ++mi)
            af[mi] = *(const short8*)(As + (wr*64 + mi*16 + c)*32 + g*8);
        #pragma unroll
        for (int ni = 0; ni < 4; ++ni)
            bfr[ni] = *(const short8*)(Bs + (wc*64 + ni*16 + c)*32 + g*8);
        #pragma unroll
        for (int mi = 0; mi < 4; ++mi)
            #pragma unroll
            for (int ni = 0; ni < 4; ++ni)
                acc[mi][ni] = __builtin_amdgcn_mfma_f32_16x16x32_bf16(
                    af[mi], bfr[ni], acc[mi][ni], 0, 0, 0);
    }

    #pragma unroll
    for (int mi = 0; mi < 4; ++mi) {
        #pragma unroll
        for (int r = 0; r < 4; ++r) {
            const int m = m0 + wr*64 + mi*16 + g*4 + r;
            #pragma unroll
            for (int ni = 0; ni < 4; ++ni) {
                const int n = n0 + wc*64 + ni*16 + c;
                outf[(size_t)m * DM + n] = acc[mi][ni][r] + bias[n];
            }
        }
    }
}

// ---------------------------------------------------------------------------
extern "C" void kernel_launch(void* const* d_in, const int* in_sizes, int n_in,
                              void* d_out, int out_size, void* d_ws, size_t ws_size,
                              hipStream_t stream) {
    const float* X  = (const float*)d_in[0];
    const float* Wq = (const float*)d_in[1];
    const float* bq = (const float*)d_in[2];
    const float* Wk = (const float*)d_in[3];
    const float* bk = (const float*)d_in[4];
    const float* Wv = (const float*)d_in[5];
    const float* bv = (const float*)d_in[6];
    const float* Wo = (const float*)d_in[7];
    const float* bo = (const float*)d_in[8];
    float* out = (float*)d_out;

    const size_t elems = (size_t)MTOT * DM;       // 3,145,728
    const size_t welems = (size_t)DM * DM;        //   589,824
    unsigned short* q    = (unsigned short*)d_ws;
    unsigned short* k    = q    + elems;
    unsigned short* v    = k    + elems;
    unsigned short* attn = v    + elems;
    unsigned short* xb   = attn + elems;
    unsigned short* wqb  = xb   + elems;
    unsigned short* wkb  = wqb  + welems;
    unsigned short* wvb  = wkb  + welems;
    unsigned short* wob  = wvb  + welems;         // total ~36.2 MB

    convert_bf16<<<dim3((XQ4 + 4*WQ4) / 256), 256, 0, stream>>>(
        X, Wq, Wk, Wv, Wo, xb, wqb, wkb, wvb, wob);
    qkv_mfma<<<dim3(6, 32, 3), 256, 0, stream>>>(
        xb, wqb, wkb, wvb, bq, bk, bv, q, k, v);
    attn_mfma<<<dim3(48, 16), 256, 0, stream>>>(q, k, v, attn);
    out_mfma<<<dim3(6, 32), 256, 0, stream>>>(attn, wob, bo, out);
}